// Round 1
// baseline (922.183 us; speedup 1.0000x reference)
//
#include <hip/hip_runtime.h>
#include <cmath>

#define T_SAMPLE 300
#define NCHUNK 75   // T / 4

struct RefK { float v[10]; };

// One step of the SLAYER spike recurrence. buf[0..9] = pending refractory.
__device__ __forceinline__ unsigned char spike_step(float u, float* buf, const RefK& rk) {
    const float um = u + buf[0];
    const bool fire = um >= 10.0f;
    const float ev = fire ? 1.0f : 0.0f;
    // buf = concat(buf[1:], 0) + ev*refk   (ev*refk is exact: ev in {0,1})
#pragma unroll
    for (int r = 0; r < 9; ++r) buf[r] = fmaf(ev, rk.v[r], buf[r + 1]);
    buf[9] = ev * rk.v[9];
    return fire ? (unsigned char)1 : (unsigned char)0;
}

// ---------------------------------------------------------------------------
// conv_u: per-timestep 2D conv (cross-correlation, pad=1), u output in fp32.
// Grid: x = t-chunk (75), y = tile*OG + og, z = local batch. Block = 256 (4 waves).
// Each wave = one group of OPT output channels over an 8x8 spatial tile;
// lane = pixel; thread computes OPT channels x 4 timesteps.
// ---------------------------------------------------------------------------
template <int IC, int OC, int K, int OH, int OW, int IH, int IW, int OPT, bool IN_F32>
__global__ __launch_bounds__(256) void conv_u_kernel(
    const void* __restrict__ in_, const float* __restrict__ W,
    float* __restrict__ U, int b0)
{
    constexpr int TH = 8, TW = 8;
    constexpr int EH = TH + K - 1, EW = TW + K - 1;
    constexpr int NTX = OW / TW, NTY = OH / TH, NT = NTX * NTY;
    constexpr int KK = K * K;
    constexpr int E = IC * EH * EW;

    __shared__ float tile[E * 4];

    const int t0 = blockIdx.x * 4;
    const int by = blockIdx.y;
    const int til = by % NT;
    const int og = by / NT;
    const int ty = til / NTX, tx = til % NTX;
    const int bl = blockIdx.z;
    const int b = b0 + bl;
    const int tid = threadIdx.x;
    const int wave = tid >> 6, lane = tid & 63;
    const int py = lane >> 3, px = lane & 7;

    // ---- stage input tile (4 timesteps) into LDS as floats ----
    const int iy0 = ty * TH - 1, ix0 = tx * TW - 1;  // PAD = 1
    for (int e = tid; e < E; e += 256) {
        const int c = e / (EH * EW);
        const int r = e % (EH * EW);
        const int iy = r / EW, ix = r % EW;
        const int gy = iy0 + iy, gx = ix0 + ix;
        float4 v = make_float4(0.f, 0.f, 0.f, 0.f);
        if (gy >= 0 && gy < IH && gx >= 0 && gx < IW) {
            const size_t base = ((((size_t)b * IC + c) * IH + gy) * IW + gx) * T_SAMPLE + t0;
            if (IN_F32) {
                v = *(const float4*)((const float*)in_ + base);
            } else {
                const uchar4 s = *(const uchar4*)((const unsigned char*)in_ + base);
                v = make_float4((float)s.x, (float)s.y, (float)s.z, (float)s.w);
            }
        }
        *(float4*)&tile[e * 4] = v;
    }
    __syncthreads();

    // ---- compute ----
    float acc[OPT][4];
#pragma unroll
    for (int j = 0; j < OPT; ++j)
#pragma unroll
        for (int k = 0; k < 4; ++k) acc[j][k] = 0.f;

    int ob = (og * 4 + wave) * OPT;
    ob = __builtin_amdgcn_readfirstlane(ob);   // wave-uniform -> scalar weight loads
    const float* Wp = W + (size_t)ob * IC * KK;

    for (int c = 0; c < IC; ++c) {
        float wc[OPT * KK];
#pragma unroll
        for (int j = 0; j < OPT; ++j)
#pragma unroll
            for (int i = 0; i < KK; ++i)
                wc[j * KK + i] = Wp[(j * IC + c) * KK + i];
#pragma unroll
        for (int dy = 0; dy < K; ++dy) {
#pragma unroll
            for (int dx = 0; dx < K; ++dx) {
                const float4 v = *(const float4*)&tile[(((c * EH) + py + dy) * EW + (px + dx)) * 4];
#pragma unroll
                for (int j = 0; j < OPT; ++j) {
                    const float w = wc[j * KK + dy * K + dx];
                    acc[j][0] = fmaf(w, v.x, acc[j][0]);
                    acc[j][1] = fmaf(w, v.y, acc[j][1]);
                    acc[j][2] = fmaf(w, v.z, acc[j][2]);
                    acc[j][3] = fmaf(w, v.w, acc[j][3]);
                }
            }
        }
    }

    const int y = ty * TH + py, x = tx * TW + px;
#pragma unroll
    for (int j = 0; j < OPT; ++j) {
        const size_t ub = ((((size_t)bl * OC + (ob + j)) * OH + y) * OW + x) * T_SAMPLE + t0;
        *(float4*)&U[ub] = make_float4(acc[j][0], acc[j][1], acc[j][2], acc[j][3]);
    }
}

// ---------------------------------------------------------------------------
// spike: per-neuron sequential scan over T; u fp32 in, spikes uint8 out.
// ---------------------------------------------------------------------------
__global__ __launch_bounds__(256) void spike_kernel(
    const float* __restrict__ U, unsigned char* __restrict__ S, int nneur, RefK rk)
{
    const int n = blockIdx.x * 256 + threadIdx.x;
    if (n >= nneur) return;
    const float4* up = (const float4*)(U + (size_t)n * T_SAMPLE);
    uchar4* sp = (uchar4*)(S + (size_t)n * T_SAMPLE);
    float buf[10];
#pragma unroll
    for (int r = 0; r < 10; ++r) buf[r] = 0.f;
    float4 nxt = up[0];
    for (int ch = 0; ch < NCHUNK; ++ch) {
        const float4 cur = nxt;
        if (ch + 1 < NCHUNK) nxt = up[ch + 1];
        uchar4 o;
        o.x = spike_step(cur.x, buf, rk);
        o.y = spike_step(cur.y, buf, rk);
        o.z = spike_step(cur.z, buf, rk);
        o.w = spike_step(cur.w, buf, rk);
        sp[ch] = o;
    }
}

// ---------------------------------------------------------------------------
// pool(2) * 11.0 fused with spike. Exact integer sums -> exact fp32.
// ---------------------------------------------------------------------------
template <int C, int H, int W>
__global__ __launch_bounds__(256) void pool_spike_kernel(
    const unsigned char* __restrict__ Sin, unsigned char* __restrict__ Sout, RefK rk)
{
    constexpr int H2 = H / 2, W2 = W / 2;
    const int n = blockIdx.x * 256 + threadIdx.x;  // over B*C*H2*W2 (exact multiple)
    const int x = n % W2;
    const int y = (n / W2) % H2;
    const int c = (n / (W2 * H2)) % C;
    const int b = n / (W2 * H2 * C);
    const size_t ib = ((((size_t)b * C + c) * H + 2 * y) * W + 2 * x) * T_SAMPLE;
    const unsigned char* p00 = Sin + ib;
    const unsigned char* p01 = p00 + T_SAMPLE;
    const unsigned char* p10 = p00 + (size_t)W * T_SAMPLE;
    const unsigned char* p11 = p10 + T_SAMPLE;
    uchar4* sp = (uchar4*)(Sout + (size_t)n * T_SAMPLE);

    float buf[10];
#pragma unroll
    for (int r = 0; r < 10; ++r) buf[r] = 0.f;

    uchar4 a = *(const uchar4*)p00, bq = *(const uchar4*)p01;
    uchar4 cq = *(const uchar4*)p10, dq = *(const uchar4*)p11;
    for (int ch = 0; ch < NCHUNK; ++ch) {
        const uchar4 ca = a, cb = bq, cc = cq, cd = dq;
        if (ch + 1 < NCHUNK) {
            const int o = (ch + 1) * 4;
            a = *(const uchar4*)(p00 + o);
            bq = *(const uchar4*)(p01 + o);
            cq = *(const uchar4*)(p10 + o);
            dq = *(const uchar4*)(p11 + o);
        }
        uchar4 o8;
        o8.x = spike_step(11.0f * (float)(ca.x + cb.x + cc.x + cd.x), buf, rk);
        o8.y = spike_step(11.0f * (float)(ca.y + cb.y + cc.y + cd.y), buf, rk);
        o8.z = spike_step(11.0f * (float)(ca.z + cb.z + cc.z + cd.z), buf, rk);
        o8.w = spike_step(11.0f * (float)(ca.w + cb.w + cc.w + cd.w), buf, rk);
        sp[ch] = o8;
    }
}

// ---------------------------------------------------------------------------
// dense u: U6[b,o,t] = sum_{site<4096} wfc[o,site] * s5[b,site,t]
// Block = 1 wave; grid (75 tchunks, 10 o, 8 b). Wave-butterfly reduction.
// ---------------------------------------------------------------------------
__global__ __launch_bounds__(64) void dense_u_kernel(
    const unsigned char* __restrict__ S5, const float* __restrict__ WFC,
    float* __restrict__ U6)
{
    const int tc = blockIdx.x, o = blockIdx.y, b = blockIdx.z;
    const int lane = threadIdx.x;
    const int t0 = tc * 4;
    float a0 = 0.f, a1 = 0.f, a2 = 0.f, a3 = 0.f;
    const unsigned char* sb = S5 + (size_t)b * 4096 * T_SAMPLE + t0;
    const float* wb = WFC + o * 4096;
    for (int i = 0; i < 64; ++i) {
        const int site = i * 64 + lane;
        const uchar4 s = *(const uchar4*)(sb + (size_t)site * T_SAMPLE);
        const float w = wb[site];
        a0 = fmaf(w, (float)s.x, a0);
        a1 = fmaf(w, (float)s.y, a1);
        a2 = fmaf(w, (float)s.z, a2);
        a3 = fmaf(w, (float)s.w, a3);
    }
#pragma unroll
    for (int m = 1; m < 64; m <<= 1) {
        a0 += __shfl_xor(a0, m, 64);
        a1 += __shfl_xor(a1, m, 64);
        a2 += __shfl_xor(a2, m, 64);
        a3 += __shfl_xor(a3, m, 64);
    }
    if (lane == 0)
        *(float4*)&U6[((size_t)b * 10 + o) * T_SAMPLE + t0] = make_float4(a0, a1, a2, a3);
}

// final spike over 80 neurons; 4-deep rolling prefetch; fp32 output.
__global__ __launch_bounds__(128) void spike6_kernel(
    const float* __restrict__ U6, float* __restrict__ Out, RefK rk)
{
    const int n = threadIdx.x;
    if (n >= 80) return;
    const float4* up = (const float4*)(U6 + (size_t)n * T_SAMPLE);
    float4* op = (float4*)(Out + (size_t)n * T_SAMPLE);
    float buf[10];
#pragma unroll
    for (int r = 0; r < 10; ++r) buf[r] = 0.f;
    float4 q0 = up[0], q1 = up[1], q2 = up[2], q3 = up[3];
    for (int ch = 0; ch < NCHUNK; ++ch) {
        const float4 cur = q0;
        q0 = q1; q1 = q2; q2 = q3;
        if (ch + 4 < NCHUNK) q3 = up[ch + 4];
        float4 o;
        o.x = (float)spike_step(cur.x, buf, rk);
        o.y = (float)spike_step(cur.y, buf, rk);
        o.z = (float)spike_step(cur.z, buf, rk);
        o.w = (float)spike_step(cur.w, buf, rk);
        op[ch] = o;
    }
}

extern "C" void kernel_launch(void* const* d_in, const int* in_sizes, int n_in,
                              void* d_out, int out_size, void* d_ws, size_t ws_size,
                              hipStream_t stream)
{
    const float* spikeIn = (const float*)d_in[0];  // [8,2,34,34,300]
    const float* w1 = (const float*)d_in[1];       // [16,2,5,5]
    const float* w2 = (const float*)d_in[2];       // [32,16,3,3]
    const float* w3 = (const float*)d_in[3];       // [64,32,3,3]
    const float* wfc = (const float*)d_in[4];      // [10,64,8,8]
    float* out = (float*)d_out;                    // [8,10,1,1,300]

    // refractory kernel tail, double -> float (matches numpy rounding)
    RefK rk;
    for (int t = 1; t <= 10; ++t)
        rk.v[t - 1] = (float)(-20.0 * (double)t * std::exp(1.0 - (double)t));

    // workspace plan (~89 MB):
    //   U  : 39.3216 MB  shared by u1(2b)/u3(4b)/u5(8b) slices
    //   A  : 39.3216 MB  s1 -> s3 -> s5 (uint8)
    //   B  :  9.8304 MB  s2 -> s4 (uint8)
    //   U6 :  0.384  MB
    char* ws = (char*)d_ws;
    const size_t U_BYTES = 39321600;
    const size_t A_BYTES = 39321600;
    const size_t B_BYTES = 9830400;
    float* U = (float*)ws;
    unsigned char* A = (unsigned char*)(ws + U_BYTES);
    unsigned char* Bb = A + A_BYTES;
    float* U6 = (float*)(Bb + B_BYTES);

    unsigned char* s1 = A;
    unsigned char* s2 = Bb;
    unsigned char* s3 = A;   // s1 dead after pool2
    unsigned char* s4 = Bb;  // s2 dead after conv2-u
    unsigned char* s5 = A;   // s3 dead after pool4

    // ---- layer 1: conv(2->16, k5) + spike, batch pairs (u slice = 39.3 MB) ----
    for (int b0 = 0; b0 < 8; b0 += 2) {
        dim3 g1(NCHUNK, 16, 2);  // 16 tiles, OG=1
        conv_u_kernel<2, 16, 5, 32, 32, 34, 34, 4, true>
            <<<g1, 256, 0, stream>>>(spikeIn, w1, U, b0);
        const int nn = 2 * 16 * 32 * 32;
        spike_kernel<<<nn / 256, 256, 0, stream>>>(
            U, s1 + (size_t)b0 * 16 * 32 * 32 * T_SAMPLE, nn, rk);
    }
    // ---- pool2 + spike ----
    pool_spike_kernel<16, 32, 32>
        <<<(8 * 16 * 16 * 16) / 256, 256, 0, stream>>>(s1, s2, rk);
    // ---- layer 2: conv(16->32, k3) + spike, batch halves ----
    for (int b0 = 0; b0 < 8; b0 += 4) {
        dim3 g2(NCHUNK, 4, 4);  // 4 tiles, OG=1
        conv_u_kernel<16, 32, 3, 16, 16, 16, 16, 8, false>
            <<<g2, 256, 0, stream>>>(s2, w2, U, b0);
        const int nn = 4 * 32 * 16 * 16;
        spike_kernel<<<nn / 256, 256, 0, stream>>>(
            U, s3 + (size_t)b0 * 32 * 16 * 16 * T_SAMPLE, nn, rk);
    }
    // ---- pool4 + spike ----
    pool_spike_kernel<32, 16, 16>
        <<<(8 * 32 * 8 * 8) / 256, 256, 0, stream>>>(s3, s4, rk);
    // ---- layer 3: conv(32->64, k3) + spike ----
    {
        dim3 g3(NCHUNK, 2, 8);  // 1 tile, OG=2
        conv_u_kernel<32, 64, 3, 8, 8, 8, 8, 8, false>
            <<<g3, 256, 0, stream>>>(s4, w3, U, 0);
        const int nn = 8 * 64 * 8 * 8;
        spike_kernel<<<nn / 256, 256, 0, stream>>>(U, s5, nn, rk);
    }
    // ---- dense + final spike ----
    dim3 g6(NCHUNK, 10, 8);
    dense_u_kernel<<<g6, 64, 0, stream>>>(s5, wfc, U6);
    spike6_kernel<<<1, 128, 0, stream>>>(U6, out, rk);
}

// Round 2
// 639.406 us; speedup vs baseline: 1.4422x; 1.4422x over previous
//
#include <hip/hip_runtime.h>
#include <cmath>

#define T_SAMPLE 300
#define NCHUNK 75   // T / 4

struct RefK { float v[10]; };

// One step of the SLAYER spike recurrence. buf[0..9] = pending refractory.
__device__ __forceinline__ unsigned char spike_step(float u, float* buf, const RefK& rk) {
    const float um = u + buf[0];
    const bool fire = um >= 10.0f;
    const float ev = fire ? 1.0f : 0.0f;
#pragma unroll
    for (int r = 0; r < 9; ++r) buf[r] = fmaf(ev, rk.v[r], buf[r + 1]);
    buf[9] = ev * rk.v[9];
    return fire ? (unsigned char)1 : (unsigned char)0;
}

// ---------------------------------------------------------------------------
// transpose input [B,2,34,34,T] f32 (values {0,1}) -> X[t][b][c][y][x] u8
// ---------------------------------------------------------------------------
__global__ __launch_bounds__(256) void transpose_in_kernel(
    const float* __restrict__ In, unsigned char* __restrict__ X)
{
    const int n = blockIdx.y * 256 + threadIdx.x;   // over 8*2*34*34 = 18496
    if (n >= 18496) return;
    const int t0 = blockIdx.x * 4;
    const float4 v = *(const float4*)(In + (size_t)n * T_SAMPLE + t0);
    X[(size_t)(t0 + 0) * 18496 + n] = (unsigned char)(v.x != 0.f);
    X[(size_t)(t0 + 1) * 18496 + n] = (unsigned char)(v.y != 0.f);
    X[(size_t)(t0 + 2) * 18496 + n] = (unsigned char)(v.z != 0.f);
    X[(size_t)(t0 + 3) * 18496 + n] = (unsigned char)(v.w != 0.f);
}

// ---------------------------------------------------------------------------
// conv_u: per-timestep 2D conv (pad=1), u8 time-major input, fp32 time-major u.
// Grid: x = t-chunk (75), y = tile*OG + og, z = local batch. Block = 256.
// Wave = OPT output channels over an 8x8 tile; lane = pixel; 4 timesteps/thread.
// ---------------------------------------------------------------------------
template <int IC, int OC, int K, int OH, int OW, int IH, int IW, int OPT, int NBL>
__global__ __launch_bounds__(256) void conv_u_kernel(
    const unsigned char* __restrict__ in_, const float* __restrict__ W,
    float* __restrict__ U, int b0)
{
    constexpr int TH = 8, TW = 8;
    constexpr int EH = TH + K - 1, EW = TW + K - 1;
    constexpr int NTX = OW / TW, NTY = OH / TH, NT = NTX * NTY;
    constexpr int KK = K * K;
    constexpr int E = IC * EH * EW;
    constexpr int PLANE_IN = 8 * IC * IH * IW;       // full-batch t-plane
    constexpr int PLANE_U = NBL * OC * OH * OW;      // slice t-plane

    __shared__ float tile[E * 4];

    const int t0 = blockIdx.x * 4;
    const int by = blockIdx.y;
    const int til = by % NT;
    const int og = by / NT;
    const int ty = til / NTX, tx = til % NTX;
    const int bl = blockIdx.z;
    const int b = b0 + bl;
    const int tid = threadIdx.x;
    const int wave = tid >> 6, lane = tid & 63;
    const int py = lane >> 3, px = lane & 7;

    // ---- stage 4 input t-planes into LDS (coalesced u8 reads) ----
    const int iy0 = ty * TH - 1, ix0 = tx * TW - 1;  // PAD = 1
    const unsigned char* ibase = in_ + (size_t)t0 * PLANE_IN + (size_t)b * IC * IH * IW;
    for (int idx = tid; idx < E * 4; idx += 256) {
        const int e = idx >> 2, tt = idx & 3;
        const int c = e / (EH * EW);
        const int r = e % (EH * EW);
        const int iy = r / EW, ix = r % EW;
        const int gy = iy0 + iy, gx = ix0 + ix;
        float v = 0.f;
        if (gy >= 0 && gy < IH && gx >= 0 && gx < IW)
            v = (float)ibase[(size_t)tt * PLANE_IN + (c * IH + gy) * IW + gx];
        tile[e * 4 + tt] = v;
    }
    __syncthreads();

    // ---- compute ----
    float acc[OPT][4];
#pragma unroll
    for (int j = 0; j < OPT; ++j)
#pragma unroll
        for (int k = 0; k < 4; ++k) acc[j][k] = 0.f;

    int ob = (og * 4 + wave) * OPT;
    ob = __builtin_amdgcn_readfirstlane(ob);
    const float* Wp = W + (size_t)ob * IC * KK;

    for (int c = 0; c < IC; ++c) {
        float wc[OPT * KK];
#pragma unroll
        for (int j = 0; j < OPT; ++j)
#pragma unroll
            for (int i = 0; i < KK; ++i)
                wc[j * KK + i] = Wp[(j * IC + c) * KK + i];
#pragma unroll
        for (int dy = 0; dy < K; ++dy) {
#pragma unroll
            for (int dx = 0; dx < K; ++dx) {
                const float4 v = *(const float4*)&tile[(((c * EH) + py + dy) * EW + (px + dx)) * 4];
#pragma unroll
                for (int j = 0; j < OPT; ++j) {
                    const float w = wc[j * KK + dy * K + dx];
                    acc[j][0] = fmaf(w, v.x, acc[j][0]);
                    acc[j][1] = fmaf(w, v.y, acc[j][1]);
                    acc[j][2] = fmaf(w, v.z, acc[j][2]);
                    acc[j][3] = fmaf(w, v.w, acc[j][3]);
                }
            }
        }
    }

    // ---- coalesced dword stores, 4 t-planes ----
    const int y = ty * TH + py, x = tx * TW + px;
#pragma unroll
    for (int j = 0; j < OPT; ++j) {
        const int nb = ((bl * OC + (ob + j)) * OH + y) * OW + x;
#pragma unroll
        for (int k = 0; k < 4; ++k)
            U[(size_t)(t0 + k) * PLANE_U + nb] = acc[j][k];
    }
}

// ---------------------------------------------------------------------------
// spike: per-neuron scan over T, time-major. Coalesced; depth-2 prefetch.
// ---------------------------------------------------------------------------
__global__ __launch_bounds__(256) void spike_kernel(
    const float* __restrict__ U, unsigned char* __restrict__ S,
    int nneur, int sstride, int soff, RefK rk)
{
    const int n = blockIdx.x * 256 + threadIdx.x;
    if (n >= nneur) return;
    const float* up = U + n;
    unsigned char* sp = S + soff + n;
    float buf[10];
#pragma unroll
    for (int r = 0; r < 10; ++r) buf[r] = 0.f;

    float A[4], B[4];
#pragma unroll
    for (int k = 0; k < 4; ++k) A[k] = up[(size_t)(0 * 4 + k) * nneur];
#pragma unroll
    for (int k = 0; k < 4; ++k) B[k] = up[(size_t)(1 * 4 + k) * nneur];

    for (int ch = 0; ch < NCHUNK - 1; ch += 2) {
        float cA[4];
#pragma unroll
        for (int k = 0; k < 4; ++k) cA[k] = A[k];
        if (ch + 2 < NCHUNK) {
#pragma unroll
            for (int k = 0; k < 4; ++k) A[k] = up[(size_t)((ch + 2) * 4 + k) * nneur];
        }
#pragma unroll
        for (int k = 0; k < 4; ++k)
            sp[(size_t)(ch * 4 + k) * sstride] = spike_step(cA[k], buf, rk);

        float cB[4];
#pragma unroll
        for (int k = 0; k < 4; ++k) cB[k] = B[k];
        if (ch + 3 < NCHUNK) {
#pragma unroll
            for (int k = 0; k < 4; ++k) B[k] = up[(size_t)((ch + 3) * 4 + k) * nneur];
        }
#pragma unroll
        for (int k = 0; k < 4; ++k)
            sp[(size_t)((ch + 1) * 4 + k) * sstride] = spike_step(cB[k], buf, rk);
    }
    // tail chunk 74 (in A)
#pragma unroll
    for (int k = 0; k < 4; ++k)
        sp[(size_t)((NCHUNK - 1) * 4 + k) * sstride] = spike_step(A[k], buf, rk);
}

// ---------------------------------------------------------------------------
// pool(2)*11 + spike, time-major, coalesced ushort loads, depth-2 prefetch.
// ---------------------------------------------------------------------------
template <int C, int H, int W>
__global__ __launch_bounds__(256) void pool_spike_kernel(
    const unsigned char* __restrict__ Sin, unsigned char* __restrict__ Sout, RefK rk)
{
    constexpr int H2 = H / 2, W2 = W / 2;
    constexpr int SIN = 8 * C * H * W;
    constexpr int SOUT = 8 * C * H2 * W2;
    const int n = blockIdx.x * 256 + threadIdx.x;   // over SOUT (exact multiple)
    const int x = n % W2;
    const int y = (n / W2) % H2;
    const int c = (n / (W2 * H2)) % C;
    const int b = n / (W2 * H2 * C);
    const unsigned char* p = Sin + (((b * C + c) * H + 2 * y) * W + 2 * x);
    unsigned char* q = Sout + n;

    float buf[10];
#pragma unroll
    for (int r = 0; r < 10; ++r) buf[r] = 0.f;

    unsigned short A0[4], A1[4], B0[4], B1[4];
#pragma unroll
    for (int k = 0; k < 4; ++k) {
        const size_t o = (size_t)(0 * 4 + k) * SIN;
        A0[k] = *(const unsigned short*)(p + o);
        A1[k] = *(const unsigned short*)(p + o + W);
    }
#pragma unroll
    for (int k = 0; k < 4; ++k) {
        const size_t o = (size_t)(1 * 4 + k) * SIN;
        B0[k] = *(const unsigned short*)(p + o);
        B1[k] = *(const unsigned short*)(p + o + W);
    }

    for (int ch = 0; ch < NCHUNK - 1; ch += 2) {
        unsigned short c0[4], c1[4];
#pragma unroll
        for (int k = 0; k < 4; ++k) { c0[k] = A0[k]; c1[k] = A1[k]; }
        if (ch + 2 < NCHUNK) {
#pragma unroll
            for (int k = 0; k < 4; ++k) {
                const size_t o = (size_t)((ch + 2) * 4 + k) * SIN;
                A0[k] = *(const unsigned short*)(p + o);
                A1[k] = *(const unsigned short*)(p + o + W);
            }
        }
#pragma unroll
        for (int k = 0; k < 4; ++k) {
            const int s = (c0[k] & 0xff) + (c0[k] >> 8) + (c1[k] & 0xff) + (c1[k] >> 8);
            q[(size_t)(ch * 4 + k) * SOUT] = spike_step(11.0f * (float)s, buf, rk);
        }
#pragma unroll
        for (int k = 0; k < 4; ++k) { c0[k] = B0[k]; c1[k] = B1[k]; }
        if (ch + 3 < NCHUNK) {
#pragma unroll
            for (int k = 0; k < 4; ++k) {
                const size_t o = (size_t)((ch + 3) * 4 + k) * SIN;
                B0[k] = *(const unsigned short*)(p + o);
                B1[k] = *(const unsigned short*)(p + o + W);
            }
        }
#pragma unroll
        for (int k = 0; k < 4; ++k) {
            const int s = (c1[k] >> 8) + (c1[k] & 0xff) + (c0[k] >> 8) + (c0[k] & 0xff);
            // keep exact reference order: a+b+c+d of small ints is exact anyway
            const int s2 = (c0[k] & 0xff) + (c0[k] >> 8) + (c1[k] & 0xff) + (c1[k] >> 8);
            (void)s;
            q[(size_t)((ch + 1) * 4 + k) * SOUT] = spike_step(11.0f * (float)s2, buf, rk);
        }
    }
    // tail chunk 74 (in A)
#pragma unroll
    for (int k = 0; k < 4; ++k) {
        const int s = (A0[k] & 0xff) + (A0[k] >> 8) + (A1[k] & 0xff) + (A1[k] >> 8);
        q[(size_t)((NCHUNK - 1) * 4 + k) * SOUT] = spike_step(11.0f * (float)s, buf, rk);
    }
}

// ---------------------------------------------------------------------------
// dense u: U6[t][b*10+o] = sum_site wfc[o,site] * s5[t][b][site]
// ---------------------------------------------------------------------------
__global__ __launch_bounds__(64) void dense_u_kernel(
    const unsigned char* __restrict__ S5, const float* __restrict__ WFC,
    float* __restrict__ U6)
{
    const int tc = blockIdx.x, o = blockIdx.y, b = blockIdx.z;
    const int lane = threadIdx.x;
    const int t0 = tc * 4;
    float a0 = 0.f, a1 = 0.f, a2 = 0.f, a3 = 0.f;
    const unsigned char* sb = S5 + b * 4096;
    const float* wb = WFC + o * 4096;
    for (int i = 0; i < 64; ++i) {
        const int site = i * 64 + lane;
        const float w = wb[site];
        a0 = fmaf(w, (float)sb[(size_t)(t0 + 0) * 32768 + site], a0);
        a1 = fmaf(w, (float)sb[(size_t)(t0 + 1) * 32768 + site], a1);
        a2 = fmaf(w, (float)sb[(size_t)(t0 + 2) * 32768 + site], a2);
        a3 = fmaf(w, (float)sb[(size_t)(t0 + 3) * 32768 + site], a3);
    }
#pragma unroll
    for (int m = 1; m < 64; m <<= 1) {
        a0 += __shfl_xor(a0, m, 64);
        a1 += __shfl_xor(a1, m, 64);
        a2 += __shfl_xor(a2, m, 64);
        a3 += __shfl_xor(a3, m, 64);
    }
    if (lane == 0) {
        const int nb = b * 10 + o;
        U6[(size_t)(t0 + 0) * 80 + nb] = a0;
        U6[(size_t)(t0 + 1) * 80 + nb] = a1;
        U6[(size_t)(t0 + 2) * 80 + nb] = a2;
        U6[(size_t)(t0 + 3) * 80 + nb] = a3;
    }
}

// final spike over 80 neurons; U6 time-major in, [n][t] fp32 out.
__global__ __launch_bounds__(128) void spike6_kernel(
    const float* __restrict__ U6, float* __restrict__ Out, RefK rk)
{
    const int n = threadIdx.x;
    if (n >= 80) return;
    const float* up = U6 + n;
    float* op = Out + (size_t)n * T_SAMPLE;
    float buf[10];
#pragma unroll
    for (int r = 0; r < 10; ++r) buf[r] = 0.f;

    float A[4], B[4];
#pragma unroll
    for (int k = 0; k < 4; ++k) A[k] = up[(size_t)(0 * 4 + k) * 80];
#pragma unroll
    for (int k = 0; k < 4; ++k) B[k] = up[(size_t)(1 * 4 + k) * 80];

    for (int ch = 0; ch < NCHUNK - 1; ch += 2) {
        float cA[4], cB[4];
#pragma unroll
        for (int k = 0; k < 4; ++k) cA[k] = A[k];
        if (ch + 2 < NCHUNK) {
#pragma unroll
            for (int k = 0; k < 4; ++k) A[k] = up[(size_t)((ch + 2) * 4 + k) * 80];
        }
#pragma unroll
        for (int k = 0; k < 4; ++k)
            op[ch * 4 + k] = (float)spike_step(cA[k], buf, rk);
#pragma unroll
        for (int k = 0; k < 4; ++k) cB[k] = B[k];
        if (ch + 3 < NCHUNK) {
#pragma unroll
            for (int k = 0; k < 4; ++k) B[k] = up[(size_t)((ch + 3) * 4 + k) * 80];
        }
#pragma unroll
        for (int k = 0; k < 4; ++k)
            op[(ch + 1) * 4 + k] = (float)spike_step(cB[k], buf, rk);
    }
#pragma unroll
    for (int k = 0; k < 4; ++k)
        op[(NCHUNK - 1) * 4 + k] = (float)spike_step(A[k], buf, rk);
}

extern "C" void kernel_launch(void* const* d_in, const int* in_sizes, int n_in,
                              void* d_out, int out_size, void* d_ws, size_t ws_size,
                              hipStream_t stream)
{
    const float* spikeIn = (const float*)d_in[0];  // [8,2,34,34,300]
    const float* w1 = (const float*)d_in[1];       // [16,2,5,5]
    const float* w2 = (const float*)d_in[2];       // [32,16,3,3]
    const float* w3 = (const float*)d_in[3];       // [64,32,3,3]
    const float* wfc = (const float*)d_in[4];      // [10,64,8,8]
    float* out = (float*)d_out;                    // [8,10,1,1,300]

    RefK rk;
    for (int t = 1; t <= 10; ++t)
        rk.v[t - 1] = (float)(-20.0 * (double)t * std::exp(1.0 - (double)t));

    // workspace (~88.6 MB), all time-major:
    //   U : 39.3216 MB  u-slices (plane 32768 f32 for all three convs)
    //   A : 39.3216 MB  s1 -> s3 -> s5 (u8)
    //   B :  9.8304 MB  X (transposed input, 5.55 MB) then s2 -> s4 (u8)
    //   U6:  0.096  MB
    char* ws = (char*)d_ws;
    const size_t U_BYTES = 39321600;
    const size_t A_BYTES = 39321600;
    const size_t B_BYTES = 9830400;
    float* U = (float*)ws;
    unsigned char* A = (unsigned char*)(ws + U_BYTES);
    unsigned char* Bb = A + A_BYTES;
    float* U6 = (float*)(Bb + B_BYTES);

    unsigned char* X = Bb;   // input transpose; dead after layer 1
    unsigned char* s1 = A;
    unsigned char* s2 = Bb;
    unsigned char* s3 = A;   // s1 dead after pool2
    unsigned char* s4 = Bb;  // s2 dead after conv2-u
    unsigned char* s5 = A;   // s3 dead after pool4

    // ---- input transpose to time-major u8 ----
    {
        dim3 g(NCHUNK, (18496 + 255) / 256);
        transpose_in_kernel<<<g, 256, 0, stream>>>(spikeIn, X);
    }
    // ---- layer 1: conv(2->16, k5) + spike, batch pairs ----
    for (int b0 = 0; b0 < 8; b0 += 2) {
        dim3 g1(NCHUNK, 16, 2);  // 16 tiles, OG=1
        conv_u_kernel<2, 16, 5, 32, 32, 34, 34, 4, 2>
            <<<g1, 256, 0, stream>>>(X, w1, U, b0);
        spike_kernel<<<32768 / 256, 256, 0, stream>>>(
            U, s1, 32768, 131072, b0 * 16384, rk);
    }
    // ---- pool2 + spike ----
    pool_spike_kernel<16, 32, 32><<<32768 / 256, 256, 0, stream>>>(s1, s2, rk);
    // ---- layer 2: conv(16->32, k3) + spike, batch halves ----
    for (int b0 = 0; b0 < 8; b0 += 4) {
        dim3 g2(NCHUNK, 4, 4);   // 4 tiles, OG=1
        conv_u_kernel<16, 32, 3, 16, 16, 16, 16, 8, 4>
            <<<g2, 256, 0, stream>>>(s2, w2, U, b0);
        spike_kernel<<<32768 / 256, 256, 0, stream>>>(
            U, s3, 32768, 65536, b0 * 8192, rk);
    }
    // ---- pool4 + spike ----
    pool_spike_kernel<32, 16, 16><<<16384 / 256, 256, 0, stream>>>(s3, s4, rk);
    // ---- layer 3: conv(32->64, k3) + spike, full batch ----
    {
        dim3 g3(NCHUNK, 2, 8);   // 1 tile, OG=2
        conv_u_kernel<32, 64, 3, 8, 8, 8, 8, 8, 8>
            <<<g3, 256, 0, stream>>>(s4, w3, U, 0);
        spike_kernel<<<32768 / 256, 256, 0, stream>>>(U, s5, 32768, 32768, 0, rk);
    }
    // ---- dense + final spike ----
    dim3 g6(NCHUNK, 10, 8);
    dense_u_kernel<<<g6, 64, 0, stream>>>(s5, wfc, U6);
    spike6_kernel<<<1, 128, 0, stream>>>(U6, out, rk);
}

// Round 3
// 402.879 us; speedup vs baseline: 2.2890x; 1.5871x over previous
//
#include <hip/hip_runtime.h>
#include <cmath>

#define T_SAMPLE 300
#define NCHUNK 75   // T / 4

struct RefK { float v[10]; };

// One step of the SLAYER spike recurrence. buf[0..9] = pending refractory.
__device__ __forceinline__ unsigned char spike_step(float u, float* buf, const RefK& rk) {
    const float um = u + buf[0];
    const bool fire = um >= 10.0f;
    const float ev = fire ? 1.0f : 0.0f;
#pragma unroll
    for (int r = 0; r < 9; ++r) buf[r] = fmaf(ev, rk.v[r], buf[r + 1]);
    buf[9] = ev * rk.v[9];
    return fire ? (unsigned char)1 : (unsigned char)0;
}

// ---------------------------------------------------------------------------
// transpose input [B,2,34,34,T] f32 ({0,1}) -> X[tchunk][n][4] u8, n = b,c,y,x
// LDS bounce so both global loads and stores are coalesced.
// ---------------------------------------------------------------------------
__global__ __launch_bounds__(256) void transpose_in_kernel(
    const float* __restrict__ In, unsigned int* __restrict__ X)
{
    __shared__ unsigned int lds[16 * NCHUNK];
    const int blk = blockIdx.x;          // 1156 blocks x 16 neurons
    const int tn = threadIdx.x >> 4;     // 0..15 neuron
    const int tq = threadIdx.x & 15;     // 0..15 t-group
    const size_t n = (size_t)blk * 16 + tn;
#pragma unroll
    for (int p = 0; p < 5; ++p) {
        const int ch = p * 16 + tq;
        if (ch < NCHUNK) {
            const float4 v = *(const float4*)(In + n * T_SAMPLE + ch * 4);
            unsigned int u = (v.x != 0.f ? 1u : 0u) | (v.y != 0.f ? 0x100u : 0u) |
                             (v.z != 0.f ? 0x10000u : 0u) | (v.w != 0.f ? 0x1000000u : 0u);
            lds[tn * NCHUNK + ch] = u;
        }
    }
    __syncthreads();
    for (int idx = threadIdx.x; idx < 16 * NCHUNK; idx += 256) {
        const int ch = idx >> 4, t2 = idx & 15;
        X[(size_t)ch * 18496 + blk * 16 + t2] = lds[t2 * NCHUNK + ch];
    }
}

// ---------------------------------------------------------------------------
// conv_u: per-timestep 2D conv (pad=1). Input: uchar4 t-chunked spikes.
// Output: float4 t-chunked u. Grid: x = tchunk, y = tile*OG+og, z = local b.
// Wave = OPT output channels over an 8x8 tile; lane = pixel.
// ---------------------------------------------------------------------------
template <int IC, int OC, int K, int OH, int OW, int IH, int IW, int OPT, int NBL>
__global__ __launch_bounds__(256) void conv_u_kernel(
    const uchar4* __restrict__ in_, const float* __restrict__ W,
    float4* __restrict__ U, int b0)
{
    constexpr int TH = 8, TW = 8;
    constexpr int EH = TH + K - 1, EW = TW + K - 1;
    constexpr int NTX = OW / TW, NTY = OH / TH, NT = NTX * NTY;
    constexpr int KK = K * K;
    constexpr int E = IC * EH * EW;
    constexpr int PLANE_IN = 8 * IC * IH * IW;   // full-batch chunk plane (uchar4)
    constexpr int PLANE_U = NBL * OC * OH * OW;  // slice chunk plane (float4)

    __shared__ float4 tile[E];

    const int tc = blockIdx.x;
    const int by = blockIdx.y;
    const int til = by % NT;
    const int og = by / NT;
    const int ty = til / NTX, tx = til % NTX;
    const int bl = blockIdx.z;
    const int b = b0 + bl;
    const int tid = threadIdx.x;
    const int wave = tid >> 6, lane = tid & 63;
    const int py = lane >> 3, px = lane & 7;

    // ---- stage: one coalesced uchar4 per element ----
    const int iy0 = ty * TH - 1, ix0 = tx * TW - 1;  // PAD = 1
    const uchar4* ib = in_ + (size_t)tc * PLANE_IN + (size_t)b * IC * IH * IW;
    for (int e = tid; e < E; e += 256) {
        const int c = e / (EH * EW);
        const int r = e % (EH * EW);
        const int iy = r / EW, ix = r % EW;
        const int gy = iy0 + iy, gx = ix0 + ix;
        float4 v = make_float4(0.f, 0.f, 0.f, 0.f);
        if ((unsigned)gy < (unsigned)IH && (unsigned)gx < (unsigned)IW) {
            const uchar4 s = ib[(c * IH + gy) * IW + gx];
            v = make_float4((float)s.x, (float)s.y, (float)s.z, (float)s.w);
        }
        tile[e] = v;
    }
    __syncthreads();

    // ---- compute ----
    float acc[OPT][4];
#pragma unroll
    for (int j = 0; j < OPT; ++j)
#pragma unroll
        for (int k = 0; k < 4; ++k) acc[j][k] = 0.f;

    int ob = (og * 4 + wave) * OPT;
    ob = __builtin_amdgcn_readfirstlane(ob);   // wave-uniform -> scalar weight loads
    const float* Wp = W + (size_t)ob * IC * KK;

    for (int c = 0; c < IC; ++c) {
#pragma unroll
        for (int dy = 0; dy < K; ++dy) {
            float wr[OPT][K];
#pragma unroll
            for (int j = 0; j < OPT; ++j)
#pragma unroll
                for (int dx = 0; dx < K; ++dx)
                    wr[j][dx] = Wp[(j * IC + c) * KK + dy * K + dx];
#pragma unroll
            for (int dx = 0; dx < K; ++dx) {
                const float4 v = tile[((c * EH) + py + dy) * EW + (px + dx)];
#pragma unroll
                for (int j = 0; j < OPT; ++j) {
                    const float w = wr[j][dx];
                    acc[j][0] = fmaf(w, v.x, acc[j][0]);
                    acc[j][1] = fmaf(w, v.y, acc[j][1]);
                    acc[j][2] = fmaf(w, v.z, acc[j][2]);
                    acc[j][3] = fmaf(w, v.w, acc[j][3]);
                }
            }
        }
    }

    const int y = ty * TH + py, x = tx * TW + px;
#pragma unroll
    for (int j = 0; j < OPT; ++j) {
        const int nb = ((bl * OC + (ob + j)) * OH + y) * OW + x;
        U[(size_t)tc * PLANE_U + nb] = make_float4(acc[j][0], acc[j][1], acc[j][2], acc[j][3]);
    }
}

// ---------------------------------------------------------------------------
// spike: per-neuron scan. float4 per chunk in, uchar4 per chunk out. Ring-8.
// ---------------------------------------------------------------------------
__global__ __launch_bounds__(256) void spike_kernel(
    const float4* __restrict__ U, uchar4* __restrict__ S,
    int nneur, int sstride, int soff, RefK rk)
{
    const int n = blockIdx.x * 256 + threadIdx.x;
    if (n >= nneur) return;
    const float4* up = U + n;
    uchar4* sp = S + soff + n;
    float buf[10];
#pragma unroll
    for (int r = 0; r < 10; ++r) buf[r] = 0.f;

    float4 ring[8];
#pragma unroll
    for (int r = 0; r < 8; ++r) ring[r] = up[(size_t)r * nneur];

#pragma unroll 8
    for (int ch = 0; ch < 72; ++ch) {
        const float4 cur = ring[ch & 7];
        const int pf = (ch + 8 < NCHUNK) ? ch + 8 : NCHUNK - 1;
        ring[ch & 7] = up[(size_t)pf * nneur];
        uchar4 o;
        o.x = spike_step(cur.x, buf, rk);
        o.y = spike_step(cur.y, buf, rk);
        o.z = spike_step(cur.z, buf, rk);
        o.w = spike_step(cur.w, buf, rk);
        sp[(size_t)ch * sstride] = o;
    }
#pragma unroll
    for (int ch = 72; ch < NCHUNK; ++ch) {
        const float4 cur = ring[ch & 7];
        uchar4 o;
        o.x = spike_step(cur.x, buf, rk);
        o.y = spike_step(cur.y, buf, rk);
        o.z = spike_step(cur.z, buf, rk);
        o.w = spike_step(cur.w, buf, rk);
        sp[(size_t)ch * sstride] = o;
    }
}

// ---------------------------------------------------------------------------
// pool(2)*11 + spike. Two 8-byte loads per chunk (x-pair rows). Ring-8.
// ---------------------------------------------------------------------------
__device__ __forceinline__ int bsum4(uint2 r0, uint2 r1, int k) {
    return (int)((r0.x >> (8 * k)) & 0xffu) + (int)((r0.y >> (8 * k)) & 0xffu)
         + (int)((r1.x >> (8 * k)) & 0xffu) + (int)((r1.y >> (8 * k)) & 0xffu);
}

template <int C, int H, int W>
__global__ __launch_bounds__(256) void pool_spike_kernel(
    const uchar4* __restrict__ Sin, uchar4* __restrict__ Sout, RefK rk)
{
    constexpr int H2 = H / 2, W2 = W / 2;
    constexpr int SIN = 8 * C * H * W;     // chunk stride (uchar4 units)
    constexpr int SOUT = 8 * C * H2 * W2;
    const int n = blockIdx.x * 256 + threadIdx.x;   // exact multiple of 256
    const int x = n % W2;
    const int y = (n / W2) % H2;
    const int c = (n / (W2 * H2)) % C;
    const int b = n / (W2 * H2 * C);
    const int base = (((b * C + c) * H + 2 * y) * W + 2 * x);
    uchar4* q = Sout + n;

    float buf[10];
#pragma unroll
    for (int r = 0; r < 10; ++r) buf[r] = 0.f;

    uint2 r0[8], r1[8];
#pragma unroll
    for (int r = 0; r < 8; ++r) {
        r0[r] = *(const uint2*)(Sin + (size_t)r * SIN + base);
        r1[r] = *(const uint2*)(Sin + (size_t)r * SIN + base + W);
    }

#pragma unroll 8
    for (int ch = 0; ch < 72; ++ch) {
        const uint2 a0 = r0[ch & 7], a1 = r1[ch & 7];
        const int pf = (ch + 8 < NCHUNK) ? ch + 8 : NCHUNK - 1;
        r0[ch & 7] = *(const uint2*)(Sin + (size_t)pf * SIN + base);
        r1[ch & 7] = *(const uint2*)(Sin + (size_t)pf * SIN + base + W);
        uchar4 o;
        o.x = spike_step(11.0f * (float)bsum4(a0, a1, 0), buf, rk);
        o.y = spike_step(11.0f * (float)bsum4(a0, a1, 1), buf, rk);
        o.z = spike_step(11.0f * (float)bsum4(a0, a1, 2), buf, rk);
        o.w = spike_step(11.0f * (float)bsum4(a0, a1, 3), buf, rk);
        q[(size_t)ch * SOUT] = o;
    }
#pragma unroll
    for (int ch = 72; ch < NCHUNK; ++ch) {
        const uint2 a0 = r0[ch & 7], a1 = r1[ch & 7];
        uchar4 o;
        o.x = spike_step(11.0f * (float)bsum4(a0, a1, 0), buf, rk);
        o.y = spike_step(11.0f * (float)bsum4(a0, a1, 1), buf, rk);
        o.z = spike_step(11.0f * (float)bsum4(a0, a1, 2), buf, rk);
        o.w = spike_step(11.0f * (float)bsum4(a0, a1, 3), buf, rk);
        q[(size_t)ch * SOUT] = o;
    }
}

// ---------------------------------------------------------------------------
// dense u: U6[tc][b*10+o][4] = sum_site wfc[o,site] * s5[tc][b*4096+site][4]
// ---------------------------------------------------------------------------
__global__ __launch_bounds__(64) void dense_u_kernel(
    const uchar4* __restrict__ S5, const float* __restrict__ WFC,
    float4* __restrict__ U6)
{
    const int tc = blockIdx.x, o = blockIdx.y, b = blockIdx.z;
    const int lane = threadIdx.x;
    float a0 = 0.f, a1 = 0.f, a2 = 0.f, a3 = 0.f;
    const uchar4* sb = S5 + (size_t)tc * 32768 + b * 4096;
    const float* wb = WFC + o * 4096;
    for (int i = 0; i < 64; ++i) {
        const int site = i * 64 + lane;
        const uchar4 s = sb[site];
        const float w = wb[site];
        a0 = fmaf(w, (float)s.x, a0);
        a1 = fmaf(w, (float)s.y, a1);
        a2 = fmaf(w, (float)s.z, a2);
        a3 = fmaf(w, (float)s.w, a3);
    }
#pragma unroll
    for (int m = 1; m < 64; m <<= 1) {
        a0 += __shfl_xor(a0, m, 64);
        a1 += __shfl_xor(a1, m, 64);
        a2 += __shfl_xor(a2, m, 64);
        a3 += __shfl_xor(a3, m, 64);
    }
    if (lane == 0)
        U6[(size_t)tc * 80 + b * 10 + o] = make_float4(a0, a1, a2, a3);
}

// final spike over 80 neurons; float4 chunks in, [n][t] fp32 out.
__global__ __launch_bounds__(128) void spike6_kernel(
    const float4* __restrict__ U6, float* __restrict__ Out, RefK rk)
{
    const int n = threadIdx.x;
    if (n >= 80) return;
    const float4* up = U6 + n;
    float* op = Out + (size_t)n * T_SAMPLE;
    float buf[10];
#pragma unroll
    for (int r = 0; r < 10; ++r) buf[r] = 0.f;

    float4 ring[8];
#pragma unroll
    for (int r = 0; r < 8; ++r) ring[r] = up[(size_t)r * 80];

#pragma unroll 8
    for (int ch = 0; ch < 72; ++ch) {
        const float4 cur = ring[ch & 7];
        const int pf = (ch + 8 < NCHUNK) ? ch + 8 : NCHUNK - 1;
        ring[ch & 7] = up[(size_t)pf * 80];
        float4 o;
        o.x = (float)spike_step(cur.x, buf, rk);
        o.y = (float)spike_step(cur.y, buf, rk);
        o.z = (float)spike_step(cur.z, buf, rk);
        o.w = (float)spike_step(cur.w, buf, rk);
        *(float4*)(op + ch * 4) = o;
    }
#pragma unroll
    for (int ch = 72; ch < NCHUNK; ++ch) {
        const float4 cur = ring[ch & 7];
        float4 o;
        o.x = (float)spike_step(cur.x, buf, rk);
        o.y = (float)spike_step(cur.y, buf, rk);
        o.z = (float)spike_step(cur.z, buf, rk);
        o.w = (float)spike_step(cur.w, buf, rk);
        *(float4*)(op + ch * 4) = o;
    }
}

extern "C" void kernel_launch(void* const* d_in, const int* in_sizes, int n_in,
                              void* d_out, int out_size, void* d_ws, size_t ws_size,
                              hipStream_t stream)
{
    const float* spikeIn = (const float*)d_in[0];  // [8,2,34,34,300]
    const float* w1 = (const float*)d_in[1];       // [16,2,5,5]
    const float* w2 = (const float*)d_in[2];       // [32,16,3,3]
    const float* w3 = (const float*)d_in[3];       // [64,32,3,3]
    const float* wfc = (const float*)d_in[4];      // [10,64,8,8]
    float* out = (float*)d_out;                    // [8,10,1,1,300]

    RefK rk;
    for (int t = 1; t <= 10; ++t)
        rk.v[t - 1] = (float)(-20.0 * (double)t * std::exp(1.0 - (double)t));

    // workspace (~88.6 MB), all t-chunked [tc][neuron][4]:
    //   U : 39.3216 MB  float4[75*32768]  (u slices for all three convs)
    //   A : 39.3216 MB  uchar4            s1 -> s3 -> s5
    //   B :  9.8304 MB  uchar4            X (5.55 MB) then s2 -> s4
    //   U6:  0.096  MB  float4[75*80]
    char* ws = (char*)d_ws;
    const size_t U_BYTES = 39321600;
    const size_t A_BYTES = 39321600;
    const size_t B_BYTES = 9830400;
    float4* U = (float4*)ws;
    uchar4* A = (uchar4*)(ws + U_BYTES);
    uchar4* Bb = (uchar4*)(ws + U_BYTES + A_BYTES);
    float4* U6 = (float4*)(ws + U_BYTES + A_BYTES + B_BYTES);

    uchar4* X = Bb;   // input transpose; dead after layer 1
    uchar4* s1 = A;
    uchar4* s2 = Bb;
    uchar4* s3 = A;   // s1 dead after pool2
    uchar4* s4 = Bb;  // s2 dead after conv2-u
    uchar4* s5 = A;   // s3 dead after pool4

    // ---- input transpose ----
    transpose_in_kernel<<<18496 / 16, 256, 0, stream>>>(spikeIn, (unsigned int*)X);

    // ---- layer 1: conv(2->16, k5) + spike, batch pairs ----
    for (int b0 = 0; b0 < 8; b0 += 2) {
        dim3 g1(NCHUNK, 16, 2);  // 16 tiles, OG=1
        conv_u_kernel<2, 16, 5, 32, 32, 34, 34, 4, 2>
            <<<g1, 256, 0, stream>>>(X, w1, U, b0);
        spike_kernel<<<32768 / 256, 256, 0, stream>>>(
            U, s1, 32768, 131072, b0 * 16384, rk);
    }
    // ---- pool2 + spike ----
    pool_spike_kernel<16, 32, 32><<<32768 / 256, 256, 0, stream>>>(s1, s2, rk);
    // ---- layer 2: conv(16->32, k3) + spike, batch halves ----
    for (int b0 = 0; b0 < 8; b0 += 4) {
        dim3 g2(NCHUNK, 4, 4);   // 4 tiles, OG=1
        conv_u_kernel<16, 32, 3, 16, 16, 16, 16, 8, 4>
            <<<g2, 256, 0, stream>>>(s2, w2, U, b0);
        spike_kernel<<<32768 / 256, 256, 0, stream>>>(
            U, s3, 32768, 65536, b0 * 8192, rk);
    }
    // ---- pool4 + spike ----
    pool_spike_kernel<32, 16, 16><<<16384 / 256, 256, 0, stream>>>(s3, s4, rk);
    // ---- layer 3: conv(32->64, k3) + spike, full batch ----
    {
        dim3 g3(NCHUNK, 2, 8);   // 1 tile, OG=2
        conv_u_kernel<32, 64, 3, 8, 8, 8, 8, 8, 8>
            <<<g3, 256, 0, stream>>>(s4, w3, U, 0);
        spike_kernel<<<32768 / 256, 256, 0, stream>>>(U, s5, 32768, 32768, 0, rk);
    }
    // ---- dense + final spike ----
    dim3 g6(NCHUNK, 10, 8);
    dense_u_kernel<<<g6, 64, 0, stream>>>(s5, wfc, U6);
    spike6_kernel<<<1, 128, 0, stream>>>(U6, out, rk);
}